// Round 12
// baseline (159.693 us; speedup 1.0000x reference)
//
#include <hip/hip_runtime.h>
#include <hip/hip_bf16.h>
#include <stdint.h>

// Problem constants (b=16, l=4096, d=256, c=256, qk_dim=256, heads=8)
// Inputs: float32. Outputs: FLOAT32:
//   out[0..65536)       k  [8,256,32]
//   out[65536..131072)  v  [8,256,32]
//   out[131072..196608) x_global [256,256]
#define DD 256
#define CC 256
#define MAXN 1024   // per-cluster list slab (mean 256, std ~16; 1024 is >40 sigma)

typedef __attribute__((ext_vector_type(8))) short bf16x8;
typedef __attribute__((ext_vector_type(4))) float f32x4;

// round-to-nearest-even f32 -> bf16; also returns the rounded value as f32
__device__ __forceinline__ unsigned short bf16_rn(float v, float& hval) {
    unsigned u = __builtin_bit_cast(unsigned, v);
    unsigned r = u + 0x7FFFu + ((u >> 16) & 1u);
    hval = __builtin_bit_cast(float, r & 0xFFFF0000u);
    return (unsigned short)(r >> 16);
}

// pack {hi16(b):hi16(a)} into one u32 (a -> low half) -- 1 v_perm_b32
__device__ __forceinline__ unsigned pack2h(unsigned a, unsigned b) {
#if __has_builtin(__builtin_amdgcn_perm)
    return __builtin_amdgcn_perm(b, a, 0x07060302u);
#else
    return (a >> 16) | (b & 0xFFFF0000u);
#endif
}

// cheap split-bf16 conversion (R3): hi = RN-bf16(x); lo = TRUNC-bf16(x-hi).
// Trunc-lo perturbs dots at 2^-17 rel; absmax 3.9e-3 passed R4-R11, determin.
__device__ __forceinline__ void cvt_split(const float4& a, const float4& b,
                                          bf16x8& hi, bf16x8& lo) {
    float f[8] = {a.x, a.y, a.z, a.w, b.x, b.y, b.z, b.w};
    unsigned hp[4], lp[4];
#pragma unroll
    for (int i = 0; i < 4; i++) {
        unsigned u0 = __builtin_bit_cast(unsigned, f[2 * i]);
        unsigned u1 = __builtin_bit_cast(unsigned, f[2 * i + 1]);
        unsigned r0 = u0 + 0x7FFFu + ((u0 >> 16) & 1u);
        unsigned r1 = u1 + 0x7FFFu + ((u1 >> 16) & 1u);
        hp[i] = pack2h(r0, r1);
        float h0 = __builtin_bit_cast(float, r0 & 0xFFFF0000u);
        float h1 = __builtin_bit_cast(float, r1 & 0xFFFF0000u);
        unsigned l0 = __builtin_bit_cast(unsigned, f[2 * i] - h0);
        unsigned l1 = __builtin_bit_cast(unsigned, f[2 * i + 1] - h1);
        lp[i] = pack2h(l0, l1);
    }
    uint4 H = {hp[0], hp[1], hp[2], hp[3]};
    uint4 L = {lp[0], lp[1], lp[2], lp[3]};
    hi = __builtin_bit_cast(bf16x8, H);
    lo = __builtin_bit_cast(bf16x8, L);
}

// ---------------------------------------------------------------------------
// K1 (unchanged from R11): normalize means; split-bf16 packed per 32-cluster
// GROUP (32KB tiles so k_assign can double-buffer in 64KB LDS):
//   mpk2[g(8)][ hi: [kc(8)][q(4)][ct(2)][m(16)][8] | lo: same ]  (32KB/group)
// cluster c = g*32 + ct*16 + m ; dim d = kc*32 + q*8 + j.  Also zero bins.
__global__ __launch_bounds__(256) void k_prep(const float* __restrict__ xm,
                                              float* __restrict__ means_n,
                                              unsigned short* __restrict__ mpk2,
                                              int* __restrict__ bins) {
    __shared__ float red[256];
    int c = blockIdx.x, t = threadIdx.x;
    float v = xm[c * DD + t];
    red[t] = v * v;
    __syncthreads();
    for (int off = 128; off > 0; off >>= 1) {
        if (t < off) red[t] += red[t + off];
        __syncthreads();
    }
    float inv = 1.0f / fmaxf(sqrtf(red[0]), 1e-12f);
    float vn = v * inv;
    means_n[c * DD + t] = vn;
    float hf; unsigned short hb = bf16_rn(vn, hf);
    float lo = vn - hf;                 // exact
    float d2; unsigned short lb = bf16_rn(lo, d2);
    int g = c >> 5, ct = (c >> 4) & 1, m = c & 15;
    int kc = t >> 5, q = (t >> 3) & 3, j = t & 7;
    size_t base = (size_t)g * 16384 + ((kc * 4 + q) * 32 + ct * 16 + m) * 8 + j;
    mpk2[base]        = hb;             // hi half
    mpk2[base + 8192] = lb;             // lo half
    if (c == 0) bins[t] = 0;
}

// ---------------------------------------------------------------------------
// K2 v15 (R12): R11 geometry (16 pts/wave, 512 thr, 2 blk/CU, 4 w/SIMD,
// 2x32KB means dbuf) but phase A = DIRECT global->register loads, no x LDS
// staging, no phase-A barriers. R11 post-mortem: doubling occupancy AND LDS
// traffic left dur flat at 43us with all pipes <=22% -> the pin is the
// phase-A staging chain: 5 barrier-drained 32KB chunks (64KB in flight/CU,
// each chunk's HBM transfer exposed at a vmcnt(0) drain). Direct loads at
// 16 waves/CU put ~256KB/CU in flight with zero barriers; means-group-0 DMA
// overlaps the whole x load. Peak extra live regs ~16 (R11 VGPR=60 -> ~85).
// Same floats, same cvt, same loop order -> outputs bit-identical (absmax
// must print exactly 0.00390625). Falsifiable: flat dur => phase-B wall,
// declare ceiling; VGPR>=128+WRITE jump => spill, revert.
__global__ __launch_bounds__(512, 4) void k_assign(
        const float* __restrict__ x,
        const unsigned short* __restrict__ mpk2,
        unsigned short* __restrict__ bkts,
        float* __restrict__ inv_norm) {
    __shared__ __align__(16) unsigned short mlds[2][16384];   // 2 x 32KB
    int t = threadIdx.x;
    int w = t >> 6, lane = t & 63;             // w in 0..7
    int m = lane & 15, q = lane >> 4;          // q in 0..3
    int bp0 = blockIdx.x * 128;                // block owns 128 points
    int p0 = bp0 + w * 16;                     // wave owns 16 points

#define DMA_MEANS(gg, bb) {                                                    \
    const unsigned short* gm_ = mpk2 + (size_t)(gg) * 16384 + w * 512 + lane * 8; \
    _Pragma("unroll")                                                          \
    for (int i = 0; i < 4; i++)                                                \
        __builtin_amdgcn_global_load_lds(                                      \
            (const __attribute__((address_space(1))) void*)(gm_ + i * 4096),   \
            (__attribute__((address_space(3))) void*)(&mlds[bb][i * 4096 + w * 512]), \
            16, 0, 0); }

    // means group 0 DMA first: streams while the x load+convert runs
    DMA_MEANS(0, 0);

    // phase A: direct global->reg loads + convert, no barriers.
    // lane (q,m): point row p0+m, elems kc*32 + q*8 + j.
    const float* xq = x + (size_t)(p0 + m) * DD + q * 8;
    bf16x8 ah[8], al[8];
    float ss0 = 0.f;
#pragma unroll
    for (int kp = 0; kp < 4; kp++) {           // 2 kc per iteration
        float4 xa0 = *(const float4*)(xq + kp * 64);
        float4 xb0 = *(const float4*)(xq + kp * 64 + 4);
        float4 xa1 = *(const float4*)(xq + kp * 64 + 32);
        float4 xb1 = *(const float4*)(xq + kp * 64 + 36);
        ss0 += xa0.x * xa0.x + xa0.y * xa0.y + xa0.z * xa0.z + xa0.w * xa0.w +
               xb0.x * xb0.x + xb0.y * xb0.y + xb0.z * xb0.z + xb0.w * xb0.w +
               xa1.x * xa1.x + xa1.y * xa1.y + xa1.z * xa1.z + xa1.w * xa1.w +
               xb1.x * xb1.x + xb1.y * xb1.y + xb1.z * xb1.z + xb1.w * xb1.w;
        cvt_split(xa0, xb0, ah[kp * 2],     al[kp * 2]);
        cvt_split(xa1, xb1, ah[kp * 2 + 1], al[kp * 2 + 1]);
    }
    // row inv-norms: lanes with same m (4 q-values) cover all 256 elems
    ss0 += __shfl_xor(ss0, 16, 64); ss0 += __shfl_xor(ss0, 32, 64);
    if (q == 0) {
        inv_norm[p0 + m] = 1.0f / fmaxf(sqrtf(ss0), 1e-12f);
    }
    __syncthreads();            // group-0 means DMA drained + all waves ready

    float bv[4]; int bi[4];
#pragma unroll
    for (int r = 0; r < 4; r++) { bv[r] = -__builtin_inff(); bi[r] = 0; }

    for (int g = 0; g < 8; g++) {
        // prefetch next group's 32KB into the other buffer
        if (g < 7) { DMA_MEANS(g + 1, (g + 1) & 1); }

        f32x4 acc[2];
        acc[0] = (f32x4){0.f, 0.f, 0.f, 0.f};
        acc[1] = (f32x4){0.f, 0.f, 0.f, 0.f};
        const unsigned short* mb = &mlds[g & 1][q * 256 + m * 8];
#pragma unroll
        for (int kc = 0; kc < 8; kc++) {
            const unsigned short* fb = mb + kc * 1024;
            bf16x8 bh[2], bl[2];
#pragma unroll
            for (int ct = 0; ct < 2; ct++) {   // hoist the 4 ds_read_b128
                bh[ct] = *(const bf16x8*)(fb + ct * 128);
                bl[ct] = *(const bf16x8*)(fb + 8192 + ct * 128);
            }
#pragma unroll
            for (int ct = 0; ct < 2; ct++) {
                acc[ct] = __builtin_amdgcn_mfma_f32_16x16x32_bf16(ah[kc], bh[ct], acc[ct], 0, 0, 0);
                acc[ct] = __builtin_amdgcn_mfma_f32_16x16x32_bf16(al[kc], bh[ct], acc[ct], 0, 0, 0);
                acc[ct] = __builtin_amdgcn_mfma_f32_16x16x32_bf16(ah[kc], bl[ct], acc[ct], 0, 0, 0);
            }
        }

        // per-lane argmax update (ascending g, ascending ct; strict > keeps
        // the lowest cluster index among exact ties)
#pragma unroll
        for (int ct = 0; ct < 2; ct++) {
            int cbase = g * 32 + ct * 16 + m;
#pragma unroll
            for (int r = 0; r < 4; r++) {
                float v2 = acc[ct][r];
                if (v2 > bv[r]) { bv[r] = v2; bi[r] = cbase; }
            }
        }
        __syncthreads();   // next-group stage complete; buffer safe to reuse
    }

    // reduce across the 16 m-lanes; tie -> lowest cluster index
#pragma unroll
    for (int mask = 1; mask < 16; mask <<= 1) {
#pragma unroll
        for (int r = 0; r < 4; r++) {
            float ov = __shfl_xor(bv[r], mask, 64);
            int   oi = __shfl_xor(bi[r], mask, 64);
            if (ov > bv[r] || (ov == bv[r] && oi < bi[r])) { bv[r] = ov; bi[r] = oi; }
        }
    }
    if (m == 0) {
#pragma unroll
        for (int r = 0; r < 4; r++) {
            bkts[p0 + q * 4 + r] = (unsigned short)bi[r];   // point q*4+r of tile
        }
    }
#undef DMA_MEANS
}

// ---------------------------------------------------------------------------
// K3: sort point indices by bucket (unchanged).
__global__ __launch_bounds__(256) void k_sort(const unsigned short* __restrict__ bkts,
                                              unsigned short* __restrict__ list,
                                              int* __restrict__ bins) {
    __shared__ int hist[256];
    __shared__ int base[256];
    __shared__ unsigned short lpos[1024];
    int t = threadIdx.x;
    hist[t] = 0;
    __syncthreads();
    int p0 = blockIdx.x * 1024;
    int bkt[4];
#pragma unroll
    for (int j = 0; j < 4; j++) {
        int p = p0 + j * 256 + t;
        int b = (int)bkts[p];
        bkt[j] = b;
        lpos[j * 256 + t] = (unsigned short)atomicAdd(&hist[b], 1);
    }
    __syncthreads();
    base[t] = hist[t] > 0 ? atomicAdd(&bins[t], hist[t]) : 0;
    __syncthreads();
#pragma unroll
    for (int j = 0; j < 4; j++) {
        int b = bkt[j];
        int slot = base[b] + (int)lpos[j * 256 + t];
        list[b * MAXN + slot] = (unsigned short)(p0 + j * 256 + t);
    }
}

// ---------------------------------------------------------------------------
// K4: gather partial sums (unchanged from R4). grid (256,4) -> 4 blocks/CU;
// each block writes a NON-atomic partial sum row into dead-workspace aliases.
__global__ __launch_bounds__(256) void k_gather(const float* __restrict__ x,
                                                const unsigned short* __restrict__ list,
                                                const int* __restrict__ bins,
                                                const float* __restrict__ inv_norm,
                                                float* __restrict__ ps0,
                                                float* __restrict__ ps1,
                                                float* __restrict__ ps2,
                                                float* __restrict__ ps3) {
    __shared__ int   plist[256];
    __shared__ float linv[256];
    int c = blockIdx.x, y = blockIdx.y, t = threadIdx.x;
    int cnt = bins[c];
    int i0 = (cnt * y) >> 2, i1 = (cnt * (y + 1)) >> 2;
    int n = i1 - i0;                       // <= 256 (cnt <= MAXN)
    for (int i = t; i < n; i += 256) {
        int p = (int)list[c * MAXN + i0 + i];
        plist[i] = p;
        linv[i]  = inv_norm[p];
    }
    __syncthreads();
    float s = 0.f;
    int i = 0;
    for (; i + 16 <= n; i += 16) {
        float xv[16], lv[16];
#pragma unroll
        for (int j = 0; j < 16; j++) {
            xv[j] = x[(size_t)plist[i + j] * DD + t];
            lv[j] = linv[i + j];
        }
#pragma unroll
        for (int j = 0; j < 16; j++) s += xv[j] * lv[j];
    }
    for (; i < n; i++) s += x[(size_t)plist[i] * DD + t] * linv[i];
    float* base = (y == 0) ? ps0 : (y == 1) ? ps1 : (y == 2) ? ps2 : ps3;
    base[c * DD + t] = s;
}

// ---------------------------------------------------------------------------
// K5: x_global = l2norm(sum of 4 partials) (or old mean if empty bin), then
// k = xg @ Wk^T, v = xg @ Wv^T in [h][c][dh] layout. All f32. 256 blocks.
// NOTE: ps3 aliases out[131072..196608) (x_global). Each thread reads
// ps3[c*DD+t] BEFORE writing out[131072+c*DD+t] at the SAME index -> safe.
__global__ __launch_bounds__(256) void k_xgkv(const float* __restrict__ ps0,
                                              const float* __restrict__ ps1,
                                              const float* __restrict__ ps2,
                                              const float* __restrict__ ps3,
                                              const int* __restrict__ bins,
                                              const float* __restrict__ means_n,
                                              const float* __restrict__ Wk,
                                              const float* __restrict__ Wv,
                                              float* __restrict__ out) {
    __shared__ float red[256];
    __shared__ __align__(16) float xr[256];
    int c = blockIdx.x, t = threadIdx.x;
    float s = ps0[c * DD + t] + ps1[c * DD + t] + ps2[c * DD + t] + ps3[c * DD + t];
    red[t] = s * s;
    __syncthreads();
    for (int off = 128; off > 0; off >>= 1) {
        if (t < off) red[t] += red[t + off];
        __syncthreads();
    }
    float g;
    if (bins[c] > 0) g = s / fmaxf(sqrtf(red[0]), 1e-12f);
    else             g = means_n[c * DD + t];
    out[131072 + c * DD + t] = g;   // output 2: x_global
    xr[t] = g;
    __syncthreads();

    float ak = 0.f, av = 0.f;
    const float4* wkp = (const float4*)(Wk + (size_t)t * DD);
    const float4* wvp = (const float4*)(Wv + (size_t)t * DD);
#pragma unroll 8
    for (int j4 = 0; j4 < 64; j4++) {
        float4 wk = wkp[j4], wv = wvp[j4];
        float4 a = *(const float4*)(xr + j4 * 4);
        ak += a.x * wk.x + a.y * wk.y + a.z * wk.z + a.w * wk.w;
        av += a.x * wv.x + a.y * wv.y + a.z * wv.z + a.w * wv.w;
    }
    int h = t >> 5, dh = t & 31;
    out[h * 8192 + c * 32 + dh]         = ak;   // output 0: k
    out[65536 + h * 8192 + c * 32 + dh] = av;   // output 1: v
}

// ---------------------------------------------------------------------------
extern "C" void kernel_launch(void* const* d_in, const int* in_sizes, int n_in,
                              void* d_out, int out_size, void* d_ws, size_t ws_size,
                              hipStream_t stream) {
    (void)in_sizes; (void)n_in; (void)out_size; (void)ws_size;
    const float* x  = (const float*)d_in[0];  // [16,4096,256] f32
    const float* xm = (const float*)d_in[1];  // [256,256] f32
    const float* Wk = (const float*)d_in[2];  // [256,256] f32
    const float* Wv = (const float*)d_in[3];  // [256,256] f32

    float* ws       = (float*)d_ws;
    float* means_n  = ws;                                        // [0,65536)
    float* inv_norm = ws + 65536;                                // [65536,131072)
    unsigned short* bkts = (unsigned short*)(ws + 131072);       // [131072,163840)
    int*   bins     = (int*)(ws + 262144);                       // [262144,262400)
    unsigned short* mpk2 = (unsigned short*)(ws + 262400);       // [262400,327936)
    unsigned short* list = (unsigned short*)(ws + 327936);       // [327936,459008)
    float* out      = (float*)d_out;
    // partial-sum rows alias memory that is dead by the time k_gather runs:
    float* ps0 = ws + 131072;    // bkts region (dead after k_sort)
    float* ps1 = ws + 196608;    // spare region
    float* ps2 = ws + 262400;    // mpk2 (dead after k_assign)
    float* ps3 = out + 131072;   // x_global slot (k_xgkv reads then overwrites)

    k_prep  <<<256, 256, 0, stream>>>(xm, means_n, mpk2, bins);
    k_assign<<<512, 512, 0, stream>>>(x, mpk2, bkts, inv_norm);
    k_sort  <<<64, 256, 0, stream>>>(bkts, list, bins);
    k_gather<<<dim3(256, 4), 256, 0, stream>>>(x, list, bins, inv_norm, ps0, ps1, ps2, ps3);
    k_xgkv  <<<256, 256, 0, stream>>>(ps0, ps1, ps2, ps3, bins, means_n, Wk, Wv, out);
}